// Round 8
// baseline (216.243 us; speedup 1.0000x reference)
//
#include <hip/hip_runtime.h>

// YOLOv1 loss: 802816 rows x 30 f32, two tensors, scalar out.
// R8: discriminating experiment. All prior structures (scattered/batched/
// DMA/staged; MLP 1-30KB/wave; occ 4-66%) land at 2.1-2.6 TB/s. The one
// untested corner: coalesced DMA staging with MANY independent streams.
// 64-thr blocks (1 wave, no barriers), 128-row tiles = exactly 30 x 1KB
// lane-contiguous global_load_lds DMAs, LDS 30720B -> 5 blocks/CU. Each
// wave drains (compiler vmcnt(0)) then computes; 5 streams/CU cover the
// drain. If this also lands ~74us, the 2.6 TB/s wall is the machine's
// ceiling for this footprint -> roofline.

#define COLS 30
#define TROWS 128                  // rows per tile
#define TBYTES (TROWS * COLS * 4)  // 15360 B per tensor per tile
#define NT 6272                    // 802816 / 128

// ---------------- per-row math on named scalars (bit-exact) ---------------
#define ROW_MATH_BODY                                                        \
    const float C = 1.0f / 7.0f;                                             \
    float conf = b2.x;                    /* T[4], exactly 0.0 or 1.0 */     \
    coord = (conf == 1.0f);                                                  \
    noo = 0.0f;                                                              \
    if (conf == 0.0f) {                                                      \
        float d4_ = a2.x - conf;                                             \
        float d9_ = a4.y - b4.y;                                             \
        noo = d4_ * d4_ + d9_ * d9_;                                         \
    }                                                                        \
    float T0 = b0.x, T1 = b0.y, T2v = b1.x, T3 = b1.y;                       \
    float tb0 = T0 * T0, tb1 = T1 * T1, tb2 = T2v * T2v, tb3 = T3 * T3;      \
    float tax = tb0 * C - tb2, tay = tb1 * C - tb3;                          \
    float tbx = tax * C + tb2, tby = tay * C + tb3;                          \
    float areaT = (tbx - tax) * (tby - tay);                                 \
    float pax0 = a0.x * C - a1.x, pay0 = a0.y * C - a1.y;                    \
    float pbx0 = pax0 * C + a1.x, pby0 = pay0 * C + a1.y;                    \
    float pax1 = a2.y * C - a3.y, pay1 = a3.x * C - a4.x;                    \
    float pbx1 = pax1 * C + a3.y, pby1 = pay1 * C + a4.x;                    \
    float ltx = fmaxf(pax0, tax), lty = fmaxf(pay0, tay);                    \
    float rbx = fminf(pbx0, tbx), rby = fminf(pby0, tby);                    \
    float wx = fmaxf(rbx - ltx, 0.0f), wy = fmaxf(rby - lty, 0.0f);          \
    float inter = wx * wy;                                                   \
    float areaP = (pbx0 - pax0) * (pby0 - pay0);                             \
    float iou0 = inter / (areaP + areaT - inter);                            \
    ltx = fmaxf(pax1, tax); lty = fmaxf(pay1, tay);                          \
    rbx = fminf(pbx1, tbx); rby = fminf(pby1, tby);                          \
    wx = fmaxf(rbx - ltx, 0.0f); wy = fmaxf(rby - lty, 0.0f);                \
    inter = wx * wy;                                                         \
    areaP = (pbx1 - pax1) * (pby1 - pay1);                                   \
    float iou1 = inter / (areaP + areaT - inter);                            \
    int idx = (iou1 > iou0) ? 1 : 0;      /* argmax, first on ties */        \
    float sx = idx ? a2.y : a0.x;                                            \
    float sy = idx ? a3.x : a0.y;                                            \
    float sw = idx ? a3.y : a1.x;                                            \
    float sh = idx ? a4.x : a1.y;                                            \
    float best = b5.x, pc = a5.x;         /* class argmax, strict > */       \
    CLS_STEP(b5.y,  a5.y)  CLS_STEP(b6.x,  a6.x)  CLS_STEP(b6.y,  a6.y)      \
    CLS_STEP(b7.x,  a7.x)  CLS_STEP(b7.y,  a7.y)  CLS_STEP(b8.x,  a8.x)      \
    CLS_STEP(b8.y,  a8.y)  CLS_STEP(b9.x,  a9.x)  CLS_STEP(b9.y,  a9.y)      \
    CLS_STEP(b10.x, a10.x) CLS_STEP(b10.y, a10.y) CLS_STEP(b11.x, a11.x)     \
    CLS_STEP(b11.y, a11.y) CLS_STEP(b12.x, a12.x) CLS_STEP(b12.y, a12.y)     \
    CLS_STEP(b13.x, a13.x) CLS_STEP(b13.y, a13.y) CLS_STEP(b14.x, a14.x)     \
    CLS_STEP(b14.y, a14.y)                                                   \
    float d0 = sx - T0, d1 = sy - T1, d2 = sw - T2v, d3 = sh - T3;           \
    float dc = pc - 1.0f;                                                    \
    r = d0 * d0 + d1 * d1 + d2 * d2 + d3 * d3 + 2.0f * dc * dc;

#define CLS_STEP(tv, pv) { float v_ = (tv); if (v_ > best) { best = v_; pc = (pv); } }

// Row compute from generic float pointers (works for LDS and global).
__device__ __forceinline__ void row_compute_ptr(
    const float* P, const float* T, bool& coord, float& r, float& noo)
{
    const float2* P2 = (const float2*)P;
    const float2* T2 = (const float2*)T;
    float2 a0 = P2[0],  a1 = P2[1],  a2 = P2[2],  a3 = P2[3],  a4 = P2[4];
    float2 a5 = P2[5],  a6 = P2[6],  a7 = P2[7],  a8 = P2[8],  a9 = P2[9];
    float2 a10 = P2[10], a11 = P2[11], a12 = P2[12], a13 = P2[13], a14 = P2[14];
    float2 b0 = T2[0],  b1 = T2[1],  b2 = T2[2],  b3 = T2[3],  b4 = T2[4];
    float2 b5 = T2[5],  b6 = T2[6],  b7 = T2[7],  b8 = T2[8],  b9 = T2[9];
    float2 b10 = T2[10], b11 = T2[11], b12 = T2[12], b13 = T2[13], b14 = T2[14];
    ROW_MATH_BODY
}

// K1: one wave per block, one 128-row tile per block.
// Stage: 15 + 15 lane-contiguous 1KB DMAs (copy-grade request pattern).
// stats[tile] = {coord count, sum coord r, noobj sum, 0}.
__global__ __launch_bounds__(64) void yolo_k1(const float* __restrict__ gp,
                                              const float* __restrict__ gt,
                                              float4* __restrict__ stats) {
    __shared__ float lds[2 * TROWS * COLS];      // 30720 B
    int tid = threadIdx.x;                        // 0..63, one wave
    long tile = blockIdx.x;
    const char* gpb = (const char*)gp + tile * (long)TBYTES;
    const char* gtb = (const char*)gt + tile * (long)TBYTES;
    char* lb = (char*)lds;
#pragma unroll
    for (int k = 0; k < 15; ++k) {
        int off = k * 1024 + tid * 16;
        __builtin_amdgcn_global_load_lds(
            (const __attribute__((address_space(1))) void*)(gpb + off),
            (__attribute__((address_space(3))) void*)(lb + k * 1024), 16, 0, 0);
    }
#pragma unroll
    for (int k = 0; k < 15; ++k) {
        int off = k * 1024 + tid * 16;
        __builtin_amdgcn_global_load_lds(
            (const __attribute__((address_space(1))) void*)(gtb + off),
            (__attribute__((address_space(3))) void*)(lb + TBYTES + k * 1024), 16, 0, 0);
    }
    // compiler inserts s_waitcnt vmcnt(0) before the first ds_read below;
    // with 5 independent blocks/CU the drain is covered by other waves.

    const float* lp = lds;
    const float* lt = lds + TROWS * COLS;
    // lane l computes rows l (A, tile rows 0..63) and l+64 (B, rows 64..127)
    bool cA, cB; float rA, rB, nA, nB;
    row_compute_ptr(lp + tid * COLS, lt + tid * COLS, cA, rA, nA);
    row_compute_ptr(lp + (tid + 64) * COLS, lt + (tid + 64) * COLS, cB, rB, nB);
    float rl = (cA ? rA : 0.0f) + (cB ? rB : 0.0f);
    float nn = nA + nB;
    int c = (int)__popcll(__ballot(cA)) + (int)__popcll(__ballot(cB));
#pragma unroll
    for (int off = 32; off > 0; off >>= 1) {
        rl += __shfl_down(rl, off);
        nn += __shfl_down(nn, off);
    }
    if (tid == 0) stats[tile] = make_float4((float)c, rl, nn, 0.0f);
}

// K2: totals + scan over 6272 tile-stats + boundary-tile (128 rows) fixup.
// Tile row order is sequential (rows 0..127), lane l of wave w covers row
// 64*w + l in phase B's recompute -> rank = wave offset + ballot prefix.
__global__ __launch_bounds__(256) void yolo_k2(const float4* __restrict__ stats,
                                               const float* __restrict__ gp,
                                               const float* __restrict__ gt,
                                               float* __restrict__ out) {
    __shared__ int   wsum[4];
    __shared__ float wf[4], wn2[4];
    __shared__ int   s_bstar, s_kstar;
    __shared__ float s_base;
    __shared__ int   s_wcnt[4];
    int tid = threadIdx.x;
    int lane = tid & 63, wave = tid >> 6;
    if (tid == 0) { s_bstar = -1; s_kstar = 0; }

    const int PER = 25;                 // 256*25 = 6400 >= 6272
    int start = tid * PER;
    int end = min(NT, start + PER);

    int cloc = 0; float nloc = 0.0f;
    for (int i = start; i < end; ++i) {
        float4 s = stats[i];
        cloc += (int)s.x; nloc += s.z;
    }

    int incl = cloc;                    // inclusive shfl scan within wave
#pragma unroll
    for (int off = 1; off < 64; off <<= 1) {
        int v = __shfl_up(incl, off);
        if (lane >= off) incl += v;
    }
    if (lane == 63) wsum[wave] = incl;
    __syncthreads();                    // also orders s_bstar init vs walk
    int woff = 0;
#pragma unroll
    for (int w = 0; w < 4; ++w) woff += (w < wave) ? wsum[w] : 0;
    int ex = woff + incl - cloc;        // exclusive global prefix
    int n_obj = wsum[0] + wsum[1] + wsum[2] + wsum[3];
    int n_half = n_obj >> 1;

    float acc = 0.0f;
    int running = ex;
    for (int i = start; i < end; ++i) {
        float4 s = stats[i];
        int ci = (int)s.x;
        if (ci > 0) {
            if (running + ci <= n_half) {
                acc += s.y;
            } else if (running < n_half) {  // exactly one thread ever
                s_bstar = i;
                s_kstar = n_half - running;
            }
        }
        running += ci;
    }

#pragma unroll
    for (int off = 32; off > 0; off >>= 1) {
        acc  += __shfl_down(acc, off);
        nloc += __shfl_down(nloc, off);
    }
    if (lane == 0) { wf[wave] = acc; wn2[wave] = nloc; }
    __syncthreads();
    if (tid == 0)
        s_base = 5.0f * (wf[0] + wf[1] + wf[2] + wf[3])
               + 0.5f * (wn2[0] + wn2[1] + wn2[2] + wn2[3]);
    __syncthreads();

    // Phase B: boundary tile fixup (128 rows; threads >=128 sit out)
    int bstar = s_bstar, kstar = s_kstar;
    float total = 0.0f;
    if (bstar >= 0) {                    // uniform branch
        bool coord = false; float r = 0.0f;
        if (tid < TROWS) {
            long row = (long)bstar * TROWS + tid;
            float nthrow;
            row_compute_ptr(gp + row * (long)COLS, gt + row * (long)COLS,
                            coord, r, nthrow);
        }
        unsigned long long bal = __ballot(coord);
        if (lane == 0) s_wcnt[wave] = (int)__popcll(bal);
        __syncthreads();
        int waveoff = 0;
#pragma unroll
        for (int w = 0; w < 4; ++w) waveoff += (w < wave) ? s_wcnt[w] : 0;
        unsigned long long below_incl =
            (lane == 63) ? bal : (bal & ((1ull << (lane + 1)) - 1ull));
        int rank = waveoff + (int)__popcll(below_incl);  // inclusive rank
        float val = (coord && rank <= kstar) ? r : 0.0f;
#pragma unroll
        for (int off = 32; off > 0; off >>= 1) val += __shfl_down(val, off);
        if (lane == 0) wf[wave] = val;
        __syncthreads();
        if (tid == 0) total = wf[0] + wf[1] + wf[2] + wf[3];
    }
    if (tid == 0) out[0] = s_base + 5.0f * total;
}

extern "C" void kernel_launch(void* const* d_in, const int* in_sizes, int n_in,
                              void* d_out, int out_size, void* d_ws, size_t ws_size,
                              hipStream_t stream) {
    (void)in_sizes; (void)n_in; (void)out_size; (void)ws_size;
    const float* p = (const float*)d_in[0];   // predictions
    const float* t = (const float*)d_in[1];   // targets
    float4* stats = (float4*)d_ws;            // 6272 * 16 B = 100352 B
    float* out = (float*)d_out;

    yolo_k1<<<NT, 64, 0, stream>>>(p, t, stats);
    yolo_k2<<<1, 256, 0, stream>>>(stats, p, t, out);
}